// Round 6
// baseline (5745.427 us; speedup 1.0000x reference)
//
#include <hip/hip_runtime.h>
#include <hip/hip_bf16.h>
#include <stdint.h>

// ---------------------------------------------------------------------------
// DeepLSTMDecoderLayer R6:
//  - GEMMs: 128x128 tile, BK=32, global_load_lds width-16 staging (m97-style)
//  - flash attention 64x64 (validated R1/R2)
//  - LSTM scan: persistent, 32 WGs. R5 post-mortem: poll fix worked (8.5->3ms);
//    remaining cost = stage count (4 barriers + LDS gather + LDS re-read BW
//    floor + 0.43us detect quantum). R6: h direct L3->VGPR (hreg[32], pinned
//    ahead of MFMA via sched_barrier), 3 barriers, s_sleep(2) detect,
//    publish (wave0) overlapped with next-step poll (wave1).
// ws layout (MiB offsets), peak ~234 MiB:
//   0 xcb(32) | 32 wlp(16) | 48 whp(8) | 56 w1t(8) | 64 w2t(8) | 72 pb(16K)
//   73 hbuf(16.04) | 90 memb(16) | 106 wt[8](16) | 122 bq | 138 bk | 154 bv
//   170 ao_s | 186 ao_t | 202 c32(32) | 234 flags(2K)
//   overlays at 90: gx f32 (90..218, after attention) ; ffn1 bf16 (90..154)
// ---------------------------------------------------------------------------

typedef unsigned short u16;
typedef unsigned int u32;
typedef unsigned long long u64;
typedef __bf16 bf16x8 __attribute__((ext_vector_type(8)));
typedef float f32x4 __attribute__((ext_vector_type(4)));
typedef int int32x4 __attribute__((ext_vector_type(4)));
typedef unsigned long long u64x2 __attribute__((ext_vector_type(2)));

#define DEV static __device__ __forceinline__

DEV u16 f2bf(float x) {
  u32 u = __builtin_bit_cast(u32, x);
  u += 0x7FFF + ((u >> 16) & 1);  // round-to-nearest-even
  return (u16)(u >> 16);
}

DEV bf16x8 ldfrag(const void* p) {
  int32x4 v = *(const int32x4*)p;
  return __builtin_bit_cast(bf16x8, v);
}

DEV bf16x8 mkfrag(u64 lo, u64 hi) {
  u64x2 v;
  v.x = lo;
  v.y = hi;
  return __builtin_bit_cast(bf16x8, v);
}

DEV f32x4 mfma_bf16(bf16x8 a, bf16x8 b, f32x4 c) {
  return __builtin_amdgcn_mfma_f32_16x16x32_bf16(a, b, c, 0, 0, 0);
}

// async global->LDS, 16B per lane; LDS dest is wave-uniform base (+lane*16 HW)
DEV void load_lds16(const u16* g, u16* l) {
  __builtin_amdgcn_global_load_lds(
      (__attribute__((address_space(1))) void*)(uintptr_t)g,
      (__attribute__((address_space(3))) void*)(uintptr_t)l, 16, 0, 0);
}

// ---------------- conversion kernels ----------------

__global__ __launch_bounds__(256) void cvt_bf16_kernel(u16* __restrict__ out,
                                                       const float* __restrict__ in,
                                                       int n4) {
  int i = blockIdx.x * 256 + threadIdx.x;
  if (i >= n4) return;
  float4 v = ((const float4*)in)[i];
  ushort4 s;
  s.x = f2bf(v.x); s.y = f2bf(v.y); s.z = f2bf(v.z); s.w = f2bf(v.w);
  ((ushort4*)out)[i] = s;
}

// x[8192][1024] f32 -> xcb[r][0..1023] with row stride 2048
__global__ __launch_bounds__(256) void cvt_x_kernel(u16* __restrict__ out,
                                                    const float* __restrict__ in) {
  int i = blockIdx.x * 256 + threadIdx.x;  // 8192*256 float4 groups
  int r = i >> 8, cg4 = i & 255;
  float4 v = ((const float4*)in)[i];
  ushort4 s;
  s.x = f2bf(v.x); s.y = f2bf(v.y); s.z = f2bf(v.z); s.w = f2bf(v.w);
  *(ushort4*)(out + (size_t)r * 2048 + cg4 * 4) = s;
}

// out[n*K + k] = in[(k+koff)*N + n] * scale   (tiled transpose-convert)
__global__ __launch_bounds__(256) void convt_kernel(u16* __restrict__ out,
                                                    const float* __restrict__ in,
                                                    int K, int N, int koff, float scale) {
  __shared__ float tile[32][33];
  const int tid = threadIdx.x;
  const int n0 = blockIdx.x * 32, k0 = blockIdx.y * 32;
  const int c = tid & 31, r = tid >> 5;
#pragma unroll
  for (int i = 0; i < 4; ++i)
    tile[r + i * 8][c] = in[(size_t)(k0 + r + i * 8 + koff) * N + n0 + c];
  __syncthreads();
#pragma unroll
  for (int i = 0; i < 4; ++i)
    out[(size_t)(n0 + r + i * 8) * K + k0 + c] = f2bf(tile[c][r + i * 8] * scale);
}

// packed LSTM weight: out[(u*4+g)*K + k] = lstm_w[(k+koff)*4096 + g*1024 + u]
// grid (32, K/32, 4)
__global__ __launch_bounds__(256) void convt_perm_kernel(u16* __restrict__ out,
                                                         const float* __restrict__ in,
                                                         int K, int koff) {
  __shared__ float tile[32][33];
  const int tid = threadIdx.x;
  const int u0 = blockIdx.x * 32, k0 = blockIdx.y * 32, g = blockIdx.z;
  const int c = tid & 31, r = tid >> 5;
#pragma unroll
  for (int i = 0; i < 4; ++i)
    tile[r + i * 8][c] = in[(size_t)(k0 + r + i * 8 + koff) * 4096 + g * 1024 + u0 + c];
  __syncthreads();
#pragma unroll
  for (int i = 0; i < 4; ++i)
    out[(size_t)((u0 + r + i * 8) * 4 + g) * K + k0 + c] = f2bf(tile[c][r + i * 8]);
}

__global__ __launch_bounds__(256) void pack_bias_kernel(float* __restrict__ out,
                                                        const float* __restrict__ in) {
  int p = blockIdx.x * 256 + threadIdx.x;  // 4096
  out[p] = in[(p & 3) * 1024 + (p >> 2)];
}

// ---------------- GEMM: C[M,N] = A[M,K] @ Bt[N,K]^T (+bias, +cacc, relu, perm)
// 128x128 tile, BK=32, global_load_lds staging. grid (N/128, M/128), 256 thr.
// PERM==2: out row r -> (r&15)*512 + (r>>4)   (t*16+b -> b*512+t)
template <int OUTBF, int ACCUM, int RELU, int PERM>
__global__ __launch_bounds__(256) void gemm_bt_kernel(
    const u16* __restrict__ A, int lda, const u16* __restrict__ Bt,
    const float* __restrict__ bias, float bscale,
    void* __restrict__ outp, int ostride,
    const float* __restrict__ cacc, int cstride, int K) {
  __shared__ u16 As[128 * 32];
  __shared__ u16 Bs[128 * 32];
  const int tid = threadIdx.x;
  const int wave = tid >> 6, lane = tid & 63;
  const int lr = lane & 15, lg = lane >> 4;
  const int m0 = blockIdx.y * 128, n0 = blockIdx.x * 128;
  const int wr = (wave >> 1) * 64, wc = (wave & 1) * 64;

  f32x4 acc[4][4] = {};

  const int sr = lane >> 2, sce = (lane & 3) * 8;
  const u16* gA = A + (size_t)(m0 + wave * 16 + sr) * lda + sce;
  const u16* gB = Bt + (size_t)(n0 + wave * 16 + sr) * K + sce;
  u16* lA = As + wave * 16 * 32;
  u16* lB = Bs + wave * 16 * 32;

  for (int k0 = 0; k0 < K; k0 += 32) {
    __syncthreads();  // previous tile's compute done
    load_lds16(gA + k0, lA);
    load_lds16(gA + k0 + (size_t)64 * lda, lA + 64 * 32);
    load_lds16(gB + k0, lB);
    load_lds16(gB + k0 + (size_t)64 * K, lB + 64 * 32);
    __syncthreads();  // compiler drains vmcnt before barrier
    bf16x8 af[4], bfr[4];
    const u16* pa = As + (wr + lr) * 32 + lg * 8;
    const u16* pb = Bs + (wc + lr) * 32 + lg * 8;
#pragma unroll
    for (int i = 0; i < 4; ++i) af[i] = ldfrag(pa + i * 16 * 32);
#pragma unroll
    for (int j = 0; j < 4; ++j) bfr[j] = ldfrag(pb + j * 16 * 32);
#pragma unroll
    for (int i = 0; i < 4; ++i)
#pragma unroll
      for (int j = 0; j < 4; ++j)
        acc[i][j] = mfma_bf16(af[i], bfr[j], acc[i][j]);
  }

  const int col0 = n0 + wc + lr;
  const int row0 = m0 + wr + lg * 4;
#pragma unroll
  for (int i = 0; i < 4; ++i) {
#pragma unroll
    for (int j = 0; j < 4; ++j) {
      const int c = col0 + j * 16;
      const float bv = bias ? bias[c] * bscale : 0.f;
#pragma unroll
      for (int ii = 0; ii < 4; ++ii) {
        const int r = row0 + i * 16 + ii;
        float v = acc[i][j][ii] + bv;
        if (ACCUM) v += cacc[(size_t)r * cstride + c];
        if (RELU) v = fmaxf(v, 0.f);
        const int rp = (PERM == 2) ? ((r & 15) * 512 + (r >> 4)) : r;
        if (OUTBF) ((u16*)outp)[(size_t)rp * ostride + c] = f2bf(v);
        else       ((float*)outp)[(size_t)rp * ostride + c] = v;
      }
    }
  }
}

// ---------------- flash attention (validated R1/R2) ----------------
template <int CAUSAL>
__global__ __launch_bounds__(256) void flash_kernel(
    const u16* __restrict__ Q, const u16* __restrict__ Kb, const u16* __restrict__ Vb,
    const float* __restrict__ sbias, u16* __restrict__ O) {
  __shared__ u16 Kl[64 * 72];
  __shared__ u16 Vt[64 * 72];
  __shared__ u16 Pl[64 * 72];
  const int tid = threadIdx.x, wave = tid >> 6, lane = tid & 63;
  const int lr = lane & 15, lg = lane >> 4;
  const int q0 = blockIdx.x * 64, hh = blockIdx.y, b = blockIdx.z;

  bf16x8 qf[2];
  {
    const u16* qp = Q + (size_t)(b * 512 + q0 + wave * 16 + lr) * 1024 + hh * 64 + lg * 8;
    qf[0] = ldfrag(qp);
    qf[1] = ldfrag(qp + 32);
  }
  f32x4 oacc[4] = {};
  float mrun[4], lsum[4];
#pragma unroll
  for (int ii = 0; ii < 4; ++ii) { mrun[ii] = -3e38f; lsum[ii] = 0.f; }

  const int ntiles = CAUSAL ? (q0 / 64 + 1) : 8;
  for (int ti = 0; ti < ntiles; ++ti) {
    const int s0 = ti * 64;
    {
      const int r = tid >> 2, ch = (tid & 3) * 16;
      const u16* kp = Kb + (size_t)(b * 512 + s0 + r) * 1024 + hh * 64 + ch;
      const u16* vp = Vb + (size_t)(b * 512 + s0 + r) * 1024 + hh * 64 + ch;
      int32x4 k0v = *(const int32x4*)kp;
      int32x4 k1v = *(const int32x4*)(kp + 8);
      int32x4 v0v = *(const int32x4*)vp;
      int32x4 v1v = *(const int32x4*)(vp + 8);
      *(int32x4*)&Kl[r * 72 + ch] = k0v;
      *(int32x4*)&Kl[r * 72 + ch + 8] = k1v;
      const u16* v0p = (const u16*)&v0v;
      const u16* v1p = (const u16*)&v1v;
#pragma unroll
      for (int j = 0; j < 8; ++j) {
        Vt[(ch + j) * 72 + r] = v0p[j];
        Vt[(ch + 8 + j) * 72 + r] = v1p[j];
      }
    }
    __syncthreads();
    f32x4 sf[4] = {};
#pragma unroll
    for (int j = 0; j < 4; ++j)
#pragma unroll
      for (int ks = 0; ks < 2; ++ks) {
        bf16x8 kf = ldfrag(&Kl[(j * 16 + lr) * 72 + ks * 32 + lg * 8]);
        sf[j] = mfma_bf16(qf[ks], kf, sf[j]);
      }
    if (!CAUSAL) {
#pragma unroll
      for (int j = 0; j < 4; ++j) {
        const float bv = sbias[b * 512 + s0 + j * 16 + lr];
#pragma unroll
        for (int ii = 0; ii < 4; ++ii) sf[j][ii] += bv;
      }
    } else {
#pragma unroll
      for (int j = 0; j < 4; ++j) {
        const int s = s0 + j * 16 + lr;
#pragma unroll
        for (int ii = 0; ii < 4; ++ii) {
          const int q = q0 + wave * 16 + lg * 4 + ii;
          if (s > q) sf[j][ii] -= 1e9f;
        }
      }
    }
    float sc[4], rs[4];
#pragma unroll
    for (int ii = 0; ii < 4; ++ii) {
      float m = fmaxf(fmaxf(sf[0][ii], sf[1][ii]), fmaxf(sf[2][ii], sf[3][ii]));
#pragma unroll
      for (int off = 1; off < 16; off <<= 1) m = fmaxf(m, __shfl_xor(m, off));
      const float mn = fmaxf(mrun[ii], m);
      sc[ii] = __expf(mrun[ii] - mn);
      mrun[ii] = mn;
      rs[ii] = 0.f;
    }
#pragma unroll
    for (int j = 0; j < 4; ++j)
#pragma unroll
      for (int ii = 0; ii < 4; ++ii) {
        const float p = __expf(sf[j][ii] - mrun[ii]);
        rs[ii] += p;
        Pl[(wave * 16 + lg * 4 + ii) * 72 + j * 16 + lr] = f2bf(p);
      }
#pragma unroll
    for (int ii = 0; ii < 4; ++ii) {
      float r = rs[ii];
#pragma unroll
      for (int off = 1; off < 16; off <<= 1) r += __shfl_xor(r, off);
      lsum[ii] = lsum[ii] * sc[ii] + r;
    }
#pragma unroll
    for (int df = 0; df < 4; ++df)
#pragma unroll
      for (int ii = 0; ii < 4; ++ii) oacc[df][ii] *= sc[ii];
    __syncthreads();
    bf16x8 pf[2];
    pf[0] = ldfrag(&Pl[(wave * 16 + lr) * 72 + lg * 8]);
    pf[1] = ldfrag(&Pl[(wave * 16 + lr) * 72 + 32 + lg * 8]);
#pragma unroll
    for (int df = 0; df < 4; ++df)
#pragma unroll
      for (int ks = 0; ks < 2; ++ks) {
        bf16x8 vf = ldfrag(&Vt[(df * 16 + lr) * 72 + ks * 32 + lg * 8]);
        oacc[df] = mfma_bf16(pf[ks], vf, oacc[df]);
      }
    __syncthreads();
  }
#pragma unroll
  for (int df = 0; df < 4; ++df)
#pragma unroll
    for (int ii = 0; ii < 4; ++ii) {
      const float v = oacc[df][ii] / lsum[ii];
      O[(size_t)(b * 512 + q0 + wave * 16 + lg * 4 + ii) * 1024 + hh * 64 + df * 16 + lr] =
          f2bf(v);
    }
}

// ---------------- persistent LSTM scan R6 ----------------
// 32 WGs x 256 thr (1/CU). WG g owns units [g*32,+32) = packed cols [g*128,+128).
// Sync: per-WG flag (plain agent store after vmcnt(0)); wave1 polls (s_sleep(2));
// wave0 publishes -- overlapped. h path: direct L3->VGPR (hreg[32], 64 u64
// bypass loads pinned ahead of the MFMA region via sched_barrier). 3 barriers.
#define SCAN_NW 32
__global__ __launch_bounds__(256, 1) void lstm_scan_kernel(
    const u16* __restrict__ Whp, const float* __restrict__ gx,
    u16* __restrict__ hbuf, u32* __restrict__ flags) {
  const int tid = threadIdx.x, wave = tid >> 6, lane = tid & 63;
  const int lr = lane & 15, lg = lane >> 4;
  const int g = blockIdx.x;
  const int colbase = g * 128 + wave * 32;  // wave's packed-col base
  __shared__ float sums[16][128];           // [batch][local pcol]
  __shared__ u64 hsh[16][8];                // [batch][32 units as 8 u64]
  const int gb = tid >> 4;                  // gate-phase batch row 0..15
  const int up = tid & 15;                  // gate-phase unit pair: 2up, 2up+1
  float cs0 = 0.f, cs1 = 0.f;

  const u16* wp0 = Whp + (size_t)(colbase + lr) * 1024 + lg * 8;
  const u16* wp1 = wp0 + 16 * 1024;
  const float* gxp = gx + (size_t)gb * 512 * 4096 + g * 128 + up * 8;

  for (int t = 0; t < 512; ++t) {
    // gx prefetch (independent of h) before poll/barrier
    const float4 gxv0 = *(const float4*)(gxp + (size_t)t * 4096);
    const float4 gxv1 = *(const float4*)(gxp + (size_t)t * 4096 + 4);
    if (t > 0) {
      if (wave == 1) {  // wave0 may still be draining its publish - overlap
        int guard = 0;
        for (;;) {
          u32 f = 0xFFFFFFFFu;
          if (lane < SCAN_NW)
            f = __hip_atomic_load(flags + lane * 16, __ATOMIC_RELAXED,
                                  __HIP_MEMORY_SCOPE_AGENT);
          if (__all((int)(f >= (u32)t))) break;
          __builtin_amdgcn_s_sleep(2);     // ~53ns cadence, 32 lanes only
          if (++guard > (1 << 24)) break;  // insurance against hang
        }
      }
      __syncthreads();  // [S0] all h(t) published & visible
    }
    // h_t -> registers: 64 independent L3 loads, pinned before MFMA region
    const u16* hp = hbuf + (size_t)t * 16384 + lr * 1024 + lg * 8;
    bf16x8 hreg[32];
#pragma unroll
    for (int kc = 0; kc < 32; ++kc) {
      u64 h0 = __hip_atomic_load((const u64*)(hp + kc * 32), __ATOMIC_RELAXED,
                                 __HIP_MEMORY_SCOPE_AGENT);
      u64 h1 = __hip_atomic_load((const u64*)(hp + kc * 32 + 4), __ATOMIC_RELAXED,
                                 __HIP_MEMORY_SCOPE_AGENT);
      hreg[kc] = mkfrag(h0, h1);
    }
    __builtin_amdgcn_sched_barrier(0);  // loads issued before any MFMA
    // g_rec = h_t @ Wh  (wave: 16 batches x 32 cols, K=1024)
    f32x4 acc0a = {}, acc0b = {}, acc1a = {}, acc1b = {};
#pragma unroll
    for (int kc = 0; kc < 32; kc += 2) {
      acc0a = mfma_bf16(hreg[kc], ldfrag(wp0 + kc * 32), acc0a);
      acc1a = mfma_bf16(hreg[kc], ldfrag(wp1 + kc * 32), acc1a);
      acc0b = mfma_bf16(hreg[kc + 1], ldfrag(wp0 + kc * 32 + 32), acc0b);
      acc1b = mfma_bf16(hreg[kc + 1], ldfrag(wp1 + kc * 32 + 32), acc1b);
    }
    const f32x4 a0 = acc0a + acc0b, a1 = acc1a + acc1b;
#pragma unroll
    for (int ii = 0; ii < 4; ++ii) {
      sums[lg * 4 + ii][wave * 32 + lr] = a0[ii];
      sums[lg * 4 + ii][wave * 32 + 16 + lr] = a1[ii];
    }
    __syncthreads();  // [S1] sums complete
    // gate phase: thread (gb, up) handles local units 2up, 2up+1
    {
      const float4 sA = *(const float4*)&sums[gb][up * 8];
      const float4 sB = *(const float4*)&sums[gb][up * 8 + 4];
      float h2[2];
      {
        const float si = sA.x + gxv0.x, sj = sA.y + gxv0.y;
        const float sf_ = sA.z + gxv0.z, so = sA.w + gxv0.w;
        const float ig = 1.f / (1.f + __expf(-si));
        const float jg = 1.f - 2.f / (__expf(2.f * sj) + 1.f);
        const float fg = 1.f / (1.f + __expf(-sf_));
        const float og = 1.f / (1.f + __expf(-so));
        cs0 = fg * cs0 + ig * jg;
        h2[0] = og * (1.f - 2.f / (__expf(2.f * cs0) + 1.f));
      }
      {
        const float si = sB.x + gxv1.x, sj = sB.y + gxv1.y;
        const float sf_ = sB.z + gxv1.z, so = sB.w + gxv1.w;
        const float ig = 1.f / (1.f + __expf(-si));
        const float jg = 1.f - 2.f / (__expf(2.f * sj) + 1.f);
        const float fg = 1.f / (1.f + __expf(-sf_));
        const float og = 1.f / (1.f + __expf(-so));
        cs1 = fg * cs1 + ig * jg;
        h2[1] = og * (1.f - 2.f / (__expf(2.f * cs1) + 1.f));
      }
      ((u32*)&hsh[gb][0])[up] = (u32)f2bf(h2[0]) | ((u32)f2bf(h2[1]) << 16);
    }
    __syncthreads();  // [S2] hsh complete
    if (wave == 0) {  // publish h(t+1); wave1 will poll next iteration
      const int sb = lane >> 2, sq = lane & 3;
      u64* dst = (u64*)(hbuf + (size_t)(t + 1) * 16384 + sb * 1024 + g * 32) + sq * 2;
      __hip_atomic_store(dst, hsh[sb][sq * 2], __ATOMIC_RELAXED,
                         __HIP_MEMORY_SCOPE_AGENT);
      __hip_atomic_store(dst + 1, hsh[sb][sq * 2 + 1], __ATOMIC_RELAXED,
                         __HIP_MEMORY_SCOPE_AGENT);
      asm volatile("s_waitcnt vmcnt(0)" ::: "memory");  // h at coherence point
      if (lane == 0)
        __hip_atomic_store(flags + g * 16, (u32)(t + 1), __ATOMIC_RELAXED,
                           __HIP_MEMORY_SCOPE_AGENT);
    }
  }
}

// ---------------- host ----------------

extern "C" void kernel_launch(void* const* d_in, const int* in_sizes, int n_in,
                              void* d_out, int out_size, void* d_ws, size_t ws_size,
                              hipStream_t stream) {
  const float* x        = (const float*)d_in[0];
  const float* mem      = (const float*)d_in[1];
  const float* src_bias = (const float*)d_in[2];
  const float* w_src_q = (const float*)d_in[4];  const float* b_src_q = (const float*)d_in[5];
  const float* w_src_k = (const float*)d_in[6];  const float* b_src_k = (const float*)d_in[7];
  const float* w_src_v = (const float*)d_in[8];  const float* b_src_v = (const float*)d_in[9];
  const float* w_src_o = (const float*)d_in[10]; const float* b_src_o = (const float*)d_in[11];
  const float* w_tgt_q = (const float*)d_in[12]; const float* b_tgt_q = (const float*)d_in[13];
  const float* w_tgt_k = (const float*)d_in[14]; const float* b_tgt_k = (const float*)d_in[15];
  const float* w_tgt_v = (const float*)d_in[16]; const float* b_tgt_v = (const float*)d_in[17];
  const float* w_tgt_o = (const float*)d_in[18]; const float* b_tgt_o = (const float*)d_in[19];
  const float* lstm_w  = (const float*)d_in[20]; const float* lstm_b  = (const float*)d_in[21];
  const float* w1 = (const float*)d_in[22]; const float* b1f = (const float*)d_in[23];
  const float* w2 = (const float*)d_in[24]; const float* b2f = (const float*)d_in[25];

  char* ws = (char*)d_ws;
  const size_t MiB = 1024ull * 1024ull;
  u16*   xcb  = (u16*)(ws + 0);             // [8192][2048]: cols 0-1023 x, 1024+ c
  u16*   wlp  = (u16*)(ws + 32 * MiB);      // [4096 packed][2048]
  u16*   whp  = (u16*)(ws + 48 * MiB);      // [4096 packed][1024]
  u16*   w1t  = (u16*)(ws + 56 * MiB);
  u16*   w2t  = (u16*)(ws + 64 * MiB);
  float* pb   = (float*)(ws + 72 * MiB);    // packed lstm bias [4096]
  u16*   hbuf = (u16*)(ws + 73 * MiB);      // [513][16][1024]
  u16*   memb = (u16*)(ws + 90 * MiB);
  u16*   wt[8];
  for (int i = 0; i < 8; ++i) wt[i] = (u16*)(ws + 106 * MiB + (size_t)i * 2 * MiB);
  u16*   bq   = (u16*)(ws + 122 * MiB);
  u16*   bk   = (u16*)(ws + 138 * MiB);
  u16*   bv   = (u16*)(ws + 154 * MiB);
  u16*   ao_s = (u16*)(ws + 170 * MiB);
  u16*   ao_t = (u16*)(ws + 186 * MiB);
  float* c32  = (float*)(ws + 202 * MiB);   // ..234
  float* gx   = (float*)(ws + 90 * MiB);    // overlay 90..218 (after attention)
  u16*   ffn1 = (u16*)(ws + 90 * MiB);      // overlay 90..154 (after scan)
  u32*   flags = (u32*)(ws + 234 * MiB);    // 32 x 64B flag lines

  // --- conversions ---
  cvt_x_kernel<<<8192, 256, 0, stream>>>(xcb, x);
  cvt_bf16_kernel<<<8192, 256, 0, stream>>>(memb, mem, 2097152);
  const dim3 g1k(32, 32);
  convt_kernel<<<g1k, 256, 0, stream>>>(wt[0], w_src_q, 1024, 1024, 0, 0.125f);
  convt_kernel<<<g1k, 256, 0, stream>>>(wt[1], w_src_k, 1024, 1024, 0, 1.f);
  convt_kernel<<<g1k, 256, 0, stream>>>(wt[2], w_src_v, 1024, 1024, 0, 1.f);
  convt_kernel<<<g1k, 256, 0, stream>>>(wt[3], w_src_o, 1024, 1024, 0, 1.f);
  convt_kernel<<<g1k, 256, 0, stream>>>(wt[4], w_tgt_q, 1024, 1024, 0, 0.125f);
  convt_kernel<<<g1k, 256, 0, stream>>>(wt[5], w_tgt_k, 1024, 1024, 0, 1.f);
  convt_kernel<<<g1k, 256, 0, stream>>>(wt[6], w_tgt_v, 1024, 1024, 0, 1.f);
  convt_kernel<<<g1k, 256, 0, stream>>>(wt[7], w_tgt_o, 1024, 1024, 0, 1.f);
  convt_perm_kernel<<<dim3(32, 64, 4), 256, 0, stream>>>(wlp, lstm_w, 2048, 0);
  convt_perm_kernel<<<dim3(32, 32, 4), 256, 0, stream>>>(whp, lstm_w, 1024, 2048);
  convt_kernel<<<dim3(128, 32), 256, 0, stream>>>(w1t, w1, 1024, 4096, 0, 1.f);
  convt_kernel<<<dim3(32, 128), 256, 0, stream>>>(w2t, w2, 4096, 1024, 0, 1.f);
  pack_bias_kernel<<<16, 256, 0, stream>>>(pb, lstm_b);
  hipMemsetAsync(hbuf, 0, 32768, stream);   // h_0 = 0
  hipMemsetAsync(flags, 0, 2048, stream);   // flags = 0 (each replay)

  const dim3 gN1(8, 64);   // N=1024
  const dim3 gN4(32, 64);  // N=4096

  // --- src attention ---
  gemm_bt_kernel<1, 0, 0, 0><<<gN1, 256, 0, stream>>>(xcb, 2048, wt[0], b_src_q, 0.125f, bq, 1024, nullptr, 0, 1024);
  gemm_bt_kernel<1, 0, 0, 0><<<gN1, 256, 0, stream>>>(memb, 1024, wt[1], b_src_k, 1.f, bk, 1024, nullptr, 0, 1024);
  gemm_bt_kernel<1, 0, 0, 0><<<gN1, 256, 0, stream>>>(memb, 1024, wt[2], b_src_v, 1.f, bv, 1024, nullptr, 0, 1024);
  flash_kernel<0><<<dim3(8, 16, 16), 256, 0, stream>>>(bq, bk, bv, src_bias, ao_s);
  // --- tgt (causal self) attention ---
  gemm_bt_kernel<1, 0, 0, 0><<<gN1, 256, 0, stream>>>(xcb, 2048, wt[4], b_tgt_q, 0.125f, bq, 1024, nullptr, 0, 1024);
  gemm_bt_kernel<1, 0, 0, 0><<<gN1, 256, 0, stream>>>(xcb, 2048, wt[5], b_tgt_k, 1.f, bk, 1024, nullptr, 0, 1024);
  gemm_bt_kernel<1, 0, 0, 0><<<gN1, 256, 0, stream>>>(xcb, 2048, wt[6], b_tgt_v, 1.f, bv, 1024, nullptr, 0, 1024);
  flash_kernel<1><<<dim3(8, 16, 16), 256, 0, stream>>>(bq, bk, bv, nullptr, ao_t);
  // --- c = ao_s@Wo_s + bo_s + ao_t@Wo_t + bo_t -> xcb cols 1024+ (bf16) ---
  gemm_bt_kernel<0, 0, 0, 0><<<gN1, 256, 0, stream>>>(ao_s, 1024, wt[3], b_src_o, 1.f, c32, 1024, nullptr, 0, 1024);
  gemm_bt_kernel<1, 1, 0, 0><<<gN1, 256, 0, stream>>>(ao_t, 1024, wt[7], b_tgt_o, 1.f, xcb + 1024, 2048, c32, 1024, 1024);
  // --- gx = [x|c] @ wlp^T + pb  (K=2048, packed cols) ---
  gemm_bt_kernel<0, 0, 0, 0><<<gN4, 256, 0, stream>>>(xcb, 2048, wlp, pb, 1.f, gx, 4096, nullptr, 0, 2048);
  // --- LSTM scan: single persistent kernel, 32 WGs (all co-resident) ---
  lstm_scan_kernel<<<dim3(SCAN_NW), 256, 0, stream>>>(whp, gx, hbuf, flags);
  // --- FFN ---
  gemm_bt_kernel<1, 0, 1, 0><<<gN4, 256, 0, stream>>>(hbuf + 16384, 1024, w1t, b1f, 1.f, ffn1, 4096, nullptr, 0, 1024);
  gemm_bt_kernel<0, 0, 0, 2><<<gN1, 256, 0, stream>>>(ffn1, 4096, w2t, b2f, 1.f, (float*)d_out, 1024, nullptr, 0, 4096);
}

// Round 7
// 3002.240 us; speedup vs baseline: 1.9137x; 1.9137x over previous
//
#include <hip/hip_runtime.h>
#include <hip/hip_bf16.h>
#include <stdint.h>

// ---------------------------------------------------------------------------
// DeepLSTMDecoderLayer R7:
//  - GEMMs: 128x128 tile, BK=32, global_load_lds width-16 staging (m97-style)
//  - flash attention 64x64 (validated R1/R2)
//  - LSTM scan: persistent, 32 WGs. R7: NO flags -- h words carry their own
//    ready-bit via sentinel (0xFFFF..: 4x bf16 NaN, impossible for finite h;
//    each u64 written by exactly one store => atomically sentinel-or-valid).
//    Split-K: each wave gathers only its 8KB K-quarter direct to registers.
//    One barrier/step (parity-double-buffered partials). Publish = plain
//    agent stores, no vmcnt drain. Sync chain = ONE L3 propagate + spin.
// ws layout (MiB offsets), peak ~234 MiB:
//   0 xcb(32) | 32 wlp(16) | 48 whp(8) | 56 w1t(8) | 64 w2t(8) | 72 pb(16K)
//   73 hbuf(16.04) | 90 memb(16) | 106 wt[8](16) | 122 bq | 138 bk | 154 bv
//   170 ao_s | 186 ao_t | 202 c32(32)
//   overlays at 90: gx f32 (90..218, after attention) ; ffn1 bf16 (90..154)
// ---------------------------------------------------------------------------

typedef unsigned short u16;
typedef unsigned int u32;
typedef unsigned long long u64;
typedef __bf16 bf16x8 __attribute__((ext_vector_type(8)));
typedef float f32x4 __attribute__((ext_vector_type(4)));
typedef int int32x4 __attribute__((ext_vector_type(4)));
typedef unsigned long long u64x2 __attribute__((ext_vector_type(2)));

#define DEV static __device__ __forceinline__

DEV u16 f2bf(float x) {
  u32 u = __builtin_bit_cast(u32, x);
  u += 0x7FFF + ((u >> 16) & 1);  // round-to-nearest-even
  return (u16)(u >> 16);
}

DEV bf16x8 ldfrag(const void* p) {
  int32x4 v = *(const int32x4*)p;
  return __builtin_bit_cast(bf16x8, v);
}

DEV bf16x8 mkfrag(u64 lo, u64 hi) {
  u64x2 v;
  v.x = lo;
  v.y = hi;
  return __builtin_bit_cast(bf16x8, v);
}

DEV f32x4 mfma_bf16(bf16x8 a, bf16x8 b, f32x4 c) {
  return __builtin_amdgcn_mfma_f32_16x16x32_bf16(a, b, c, 0, 0, 0);
}

// async global->LDS, 16B per lane; LDS dest is wave-uniform base (+lane*16 HW)
DEV void load_lds16(const u16* g, u16* l) {
  __builtin_amdgcn_global_load_lds(
      (__attribute__((address_space(1))) void*)(uintptr_t)g,
      (__attribute__((address_space(3))) void*)(uintptr_t)l, 16, 0, 0);
}

// ---------------- conversion kernels ----------------

__global__ __launch_bounds__(256) void cvt_bf16_kernel(u16* __restrict__ out,
                                                       const float* __restrict__ in,
                                                       int n4) {
  int i = blockIdx.x * 256 + threadIdx.x;
  if (i >= n4) return;
  float4 v = ((const float4*)in)[i];
  ushort4 s;
  s.x = f2bf(v.x); s.y = f2bf(v.y); s.z = f2bf(v.z); s.w = f2bf(v.w);
  ((ushort4*)out)[i] = s;
}

// x[8192][1024] f32 -> xcb[r][0..1023] with row stride 2048
__global__ __launch_bounds__(256) void cvt_x_kernel(u16* __restrict__ out,
                                                    const float* __restrict__ in) {
  int i = blockIdx.x * 256 + threadIdx.x;  // 8192*256 float4 groups
  int r = i >> 8, cg4 = i & 255;
  float4 v = ((const float4*)in)[i];
  ushort4 s;
  s.x = f2bf(v.x); s.y = f2bf(v.y); s.z = f2bf(v.z); s.w = f2bf(v.w);
  *(ushort4*)(out + (size_t)r * 2048 + cg4 * 4) = s;
}

// out[n*K + k] = in[(k+koff)*N + n] * scale   (tiled transpose-convert)
__global__ __launch_bounds__(256) void convt_kernel(u16* __restrict__ out,
                                                    const float* __restrict__ in,
                                                    int K, int N, int koff, float scale) {
  __shared__ float tile[32][33];
  const int tid = threadIdx.x;
  const int n0 = blockIdx.x * 32, k0 = blockIdx.y * 32;
  const int c = tid & 31, r = tid >> 5;
#pragma unroll
  for (int i = 0; i < 4; ++i)
    tile[r + i * 8][c] = in[(size_t)(k0 + r + i * 8 + koff) * N + n0 + c];
  __syncthreads();
#pragma unroll
  for (int i = 0; i < 4; ++i)
    out[(size_t)(n0 + r + i * 8) * K + k0 + c] = f2bf(tile[c][r + i * 8] * scale);
}

// packed LSTM weight: out[(u*4+g)*K + k] = lstm_w[(k+koff)*4096 + g*1024 + u]
// grid (32, K/32, 4)
__global__ __launch_bounds__(256) void convt_perm_kernel(u16* __restrict__ out,
                                                         const float* __restrict__ in,
                                                         int K, int koff) {
  __shared__ float tile[32][33];
  const int tid = threadIdx.x;
  const int u0 = blockIdx.x * 32, k0 = blockIdx.y * 32, g = blockIdx.z;
  const int c = tid & 31, r = tid >> 5;
#pragma unroll
  for (int i = 0; i < 4; ++i)
    tile[r + i * 8][c] = in[(size_t)(k0 + r + i * 8 + koff) * 4096 + g * 1024 + u0 + c];
  __syncthreads();
#pragma unroll
  for (int i = 0; i < 4; ++i)
    out[(size_t)((u0 + r + i * 8) * 4 + g) * K + k0 + c] = f2bf(tile[c][r + i * 8]);
}

__global__ __launch_bounds__(256) void pack_bias_kernel(float* __restrict__ out,
                                                        const float* __restrict__ in) {
  int p = blockIdx.x * 256 + threadIdx.x;  // 4096
  out[p] = in[(p & 3) * 1024 + (p >> 2)];
}

// ---------------- GEMM: C[M,N] = A[M,K] @ Bt[N,K]^T (+bias, +cacc, relu, perm)
// 128x128 tile, BK=32, global_load_lds staging. grid (N/128, M/128), 256 thr.
// PERM==2: out row r -> (r&15)*512 + (r>>4)   (t*16+b -> b*512+t)
template <int OUTBF, int ACCUM, int RELU, int PERM>
__global__ __launch_bounds__(256) void gemm_bt_kernel(
    const u16* __restrict__ A, int lda, const u16* __restrict__ Bt,
    const float* __restrict__ bias, float bscale,
    void* __restrict__ outp, int ostride,
    const float* __restrict__ cacc, int cstride, int K) {
  __shared__ u16 As[128 * 32];
  __shared__ u16 Bs[128 * 32];
  const int tid = threadIdx.x;
  const int wave = tid >> 6, lane = tid & 63;
  const int lr = lane & 15, lg = lane >> 4;
  const int m0 = blockIdx.y * 128, n0 = blockIdx.x * 128;
  const int wr = (wave >> 1) * 64, wc = (wave & 1) * 64;

  f32x4 acc[4][4] = {};

  const int sr = lane >> 2, sce = (lane & 3) * 8;
  const u16* gA = A + (size_t)(m0 + wave * 16 + sr) * lda + sce;
  const u16* gB = Bt + (size_t)(n0 + wave * 16 + sr) * K + sce;
  u16* lA = As + wave * 16 * 32;
  u16* lB = Bs + wave * 16 * 32;

  for (int k0 = 0; k0 < K; k0 += 32) {
    __syncthreads();  // previous tile's compute done
    load_lds16(gA + k0, lA);
    load_lds16(gA + k0 + (size_t)64 * lda, lA + 64 * 32);
    load_lds16(gB + k0, lB);
    load_lds16(gB + k0 + (size_t)64 * K, lB + 64 * 32);
    __syncthreads();  // compiler drains vmcnt before barrier
    bf16x8 af[4], bfr[4];
    const u16* pa = As + (wr + lr) * 32 + lg * 8;
    const u16* pb = Bs + (wc + lr) * 32 + lg * 8;
#pragma unroll
    for (int i = 0; i < 4; ++i) af[i] = ldfrag(pa + i * 16 * 32);
#pragma unroll
    for (int j = 0; j < 4; ++j) bfr[j] = ldfrag(pb + j * 16 * 32);
#pragma unroll
    for (int i = 0; i < 4; ++i)
#pragma unroll
      for (int j = 0; j < 4; ++j)
        acc[i][j] = mfma_bf16(af[i], bfr[j], acc[i][j]);
  }

  const int col0 = n0 + wc + lr;
  const int row0 = m0 + wr + lg * 4;
#pragma unroll
  for (int i = 0; i < 4; ++i) {
#pragma unroll
    for (int j = 0; j < 4; ++j) {
      const int c = col0 + j * 16;
      const float bv = bias ? bias[c] * bscale : 0.f;
#pragma unroll
      for (int ii = 0; ii < 4; ++ii) {
        const int r = row0 + i * 16 + ii;
        float v = acc[i][j][ii] + bv;
        if (ACCUM) v += cacc[(size_t)r * cstride + c];
        if (RELU) v = fmaxf(v, 0.f);
        const int rp = (PERM == 2) ? ((r & 15) * 512 + (r >> 4)) : r;
        if (OUTBF) ((u16*)outp)[(size_t)rp * ostride + c] = f2bf(v);
        else       ((float*)outp)[(size_t)rp * ostride + c] = v;
      }
    }
  }
}

// ---------------- flash attention (validated R1/R2) ----------------
template <int CAUSAL>
__global__ __launch_bounds__(256) void flash_kernel(
    const u16* __restrict__ Q, const u16* __restrict__ Kb, const u16* __restrict__ Vb,
    const float* __restrict__ sbias, u16* __restrict__ O) {
  __shared__ u16 Kl[64 * 72];
  __shared__ u16 Vt[64 * 72];
  __shared__ u16 Pl[64 * 72];
  const int tid = threadIdx.x, wave = tid >> 6, lane = tid & 63;
  const int lr = lane & 15, lg = lane >> 4;
  const int q0 = blockIdx.x * 64, hh = blockIdx.y, b = blockIdx.z;

  bf16x8 qf[2];
  {
    const u16* qp = Q + (size_t)(b * 512 + q0 + wave * 16 + lr) * 1024 + hh * 64 + lg * 8;
    qf[0] = ldfrag(qp);
    qf[1] = ldfrag(qp + 32);
  }
  f32x4 oacc[4] = {};
  float mrun[4], lsum[4];
#pragma unroll
  for (int ii = 0; ii < 4; ++ii) { mrun[ii] = -3e38f; lsum[ii] = 0.f; }

  const int ntiles = CAUSAL ? (q0 / 64 + 1) : 8;
  for (int ti = 0; ti < ntiles; ++ti) {
    const int s0 = ti * 64;
    {
      const int r = tid >> 2, ch = (tid & 3) * 16;
      const u16* kp = Kb + (size_t)(b * 512 + s0 + r) * 1024 + hh * 64 + ch;
      const u16* vp = Vb + (size_t)(b * 512 + s0 + r) * 1024 + hh * 64 + ch;
      int32x4 k0v = *(const int32x4*)kp;
      int32x4 k1v = *(const int32x4*)(kp + 8);
      int32x4 v0v = *(const int32x4*)vp;
      int32x4 v1v = *(const int32x4*)(vp + 8);
      *(int32x4*)&Kl[r * 72 + ch] = k0v;
      *(int32x4*)&Kl[r * 72 + ch + 8] = k1v;
      const u16* v0p = (const u16*)&v0v;
      const u16* v1p = (const u16*)&v1v;
#pragma unroll
      for (int j = 0; j < 8; ++j) {
        Vt[(ch + j) * 72 + r] = v0p[j];
        Vt[(ch + 8 + j) * 72 + r] = v1p[j];
      }
    }
    __syncthreads();
    f32x4 sf[4] = {};
#pragma unroll
    for (int j = 0; j < 4; ++j)
#pragma unroll
      for (int ks = 0; ks < 2; ++ks) {
        bf16x8 kf = ldfrag(&Kl[(j * 16 + lr) * 72 + ks * 32 + lg * 8]);
        sf[j] = mfma_bf16(qf[ks], kf, sf[j]);
      }
    if (!CAUSAL) {
#pragma unroll
      for (int j = 0; j < 4; ++j) {
        const float bv = sbias[b * 512 + s0 + j * 16 + lr];
#pragma unroll
        for (int ii = 0; ii < 4; ++ii) sf[j][ii] += bv;
      }
    } else {
#pragma unroll
      for (int j = 0; j < 4; ++j) {
        const int s = s0 + j * 16 + lr;
#pragma unroll
        for (int ii = 0; ii < 4; ++ii) {
          const int q = q0 + wave * 16 + lg * 4 + ii;
          if (s > q) sf[j][ii] -= 1e9f;
        }
      }
    }
    float sc[4], rs[4];
#pragma unroll
    for (int ii = 0; ii < 4; ++ii) {
      float m = fmaxf(fmaxf(sf[0][ii], sf[1][ii]), fmaxf(sf[2][ii], sf[3][ii]));
#pragma unroll
      for (int off = 1; off < 16; off <<= 1) m = fmaxf(m, __shfl_xor(m, off));
      const float mn = fmaxf(mrun[ii], m);
      sc[ii] = __expf(mrun[ii] - mn);
      mrun[ii] = mn;
      rs[ii] = 0.f;
    }
#pragma unroll
    for (int j = 0; j < 4; ++j)
#pragma unroll
      for (int ii = 0; ii < 4; ++ii) {
        const float p = __expf(sf[j][ii] - mrun[ii]);
        rs[ii] += p;
        Pl[(wave * 16 + lg * 4 + ii) * 72 + j * 16 + lr] = f2bf(p);
      }
#pragma unroll
    for (int ii = 0; ii < 4; ++ii) {
      float r = rs[ii];
#pragma unroll
      for (int off = 1; off < 16; off <<= 1) r += __shfl_xor(r, off);
      lsum[ii] = lsum[ii] * sc[ii] + r;
    }
#pragma unroll
    for (int df = 0; df < 4; ++df)
#pragma unroll
      for (int ii = 0; ii < 4; ++ii) oacc[df][ii] *= sc[ii];
    __syncthreads();
    bf16x8 pf[2];
    pf[0] = ldfrag(&Pl[(wave * 16 + lr) * 72 + lg * 8]);
    pf[1] = ldfrag(&Pl[(wave * 16 + lr) * 72 + 32 + lg * 8]);
#pragma unroll
    for (int df = 0; df < 4; ++df)
#pragma unroll
      for (int ks = 0; ks < 2; ++ks) {
        bf16x8 vf = ldfrag(&Vt[(df * 16 + lr) * 72 + ks * 32 + lg * 8]);
        oacc[df] = mfma_bf16(pf[ks], vf, oacc[df]);
      }
    __syncthreads();
  }
#pragma unroll
  for (int df = 0; df < 4; ++df)
#pragma unroll
    for (int ii = 0; ii < 4; ++ii) {
      const float v = oacc[df][ii] / lsum[ii];
      O[(size_t)(b * 512 + q0 + wave * 16 + lg * 4 + ii) * 1024 + hh * 64 + df * 16 + lr] =
          f2bf(v);
    }
}

// ---------------- persistent LSTM scan R7: sentinel data-poll ----------------
// 32 WGs x 256 thr (1/CU). WG g owns units [g*32,+32) = packed cols [g*128,+128).
// Split-K: wave w computes ALL 128 pcols over K in [w*256,+256); gathers its
// own 8KB of h(t) (16 rows x 256 cols) direct to regs, spinning on sentinel
// (0xFF..F = 4x bf16 NaN; finite h can never encode it; every u64 written by
// one store -> atomically valid). Partials -> parity LDS; ONE barrier/step.
// Publish: gate threads shfl-pair into u64, plain agent store, no drain.
#define SCAN_NW 32
__global__ __launch_bounds__(256, 1) void lstm_scan_kernel(
    const u16* __restrict__ Whp, const float* __restrict__ gx,
    u16* __restrict__ hbuf) {
  const int tid = threadIdx.x, wave = tid >> 6, lane = tid & 63;
  const int lr = lane & 15, lg = lane >> 4;
  const int g = blockIdx.x;
  __shared__ float part[2][4][16][128];  // [parity][wave][batch][pcol] = 64 KB
  const int gb = tid >> 4;               // gate-phase batch row 0..15
  const int up = tid & 15;               // gate-phase unit pair: 2up, 2up+1
  float cs0 = 0.f, cs1 = 0.f;
  const u64 SENT = 0xFFFFFFFFFFFFFFFFull;

  // B-frag base: col-tile j (16 pcols), chunk kc -> wbase + j*16*1024 + kc*32
  const u16* wbase = Whp + (size_t)(g * 128 + lr) * 1024 + wave * 256 + lg * 8;
  const float* gxp = gx + (size_t)gb * 512 * 4096 + g * 128 + up * 8;

  for (int t = 0; t < 512; ++t) {
    // gx prefetch (independent of h)
    const float4 gxv0 = *(const float4*)(gxp + (size_t)t * 4096);
    const float4 gxv1 = *(const float4*)(gxp + (size_t)t * 4096 + 4);
    // gather this wave's K-quarter of h(t): 16 u64/lane, spin on sentinel
    const u16* hp = hbuf + (size_t)t * 16384 + lr * 1024 + wave * 256 + lg * 8;
    u64 hw[16];
#pragma unroll
    for (int kc = 0; kc < 8; ++kc) {
      hw[kc * 2] = __hip_atomic_load((const u64*)(hp + kc * 32),
                                     __ATOMIC_RELAXED, __HIP_MEMORY_SCOPE_AGENT);
      hw[kc * 2 + 1] = __hip_atomic_load((const u64*)(hp + kc * 32 + 4),
                                         __ATOMIC_RELAXED, __HIP_MEMORY_SCOPE_AGENT);
    }
    {
      int guard = 0;
      for (;;) {
        bool ok = true;
#pragma unroll
        for (int i = 0; i < 16; ++i) ok &= (hw[i] != SENT);
        if (__all((int)ok)) break;
        __builtin_amdgcn_s_sleep(4);
        if (++guard > (1 << 20)) break;  // insurance against hang
        // reload only still-sentinel words (exec-masked; no line storm)
#pragma unroll
        for (int kc = 0; kc < 8; ++kc) {
          if (hw[kc * 2] == SENT)
            hw[kc * 2] = __hip_atomic_load((const u64*)(hp + kc * 32),
                                           __ATOMIC_RELAXED, __HIP_MEMORY_SCOPE_AGENT);
          if (hw[kc * 2 + 1] == SENT)
            hw[kc * 2 + 1] = __hip_atomic_load((const u64*)(hp + kc * 32 + 4),
                                               __ATOMIC_RELAXED, __HIP_MEMORY_SCOPE_AGENT);
        }
      }
    }
    // partial GEMM: this wave's K-quarter, all 128 pcols, 16 batches
    f32x4 acc[8] = {};
#pragma unroll
    for (int kc = 0; kc < 8; ++kc) {
      const bf16x8 hf = mkfrag(hw[kc * 2], hw[kc * 2 + 1]);
#pragma unroll
      for (int j = 0; j < 8; ++j)
        acc[j] = mfma_bf16(hf, ldfrag(wbase + j * 16 * 1024 + kc * 32), acc[j]);
    }
    const int p = t & 1;
#pragma unroll
    for (int j = 0; j < 8; ++j)
#pragma unroll
      for (int ii = 0; ii < 4; ++ii)
        part[p][wave][lg * 4 + ii][j * 16 + lr] = acc[j][ii];
    __syncthreads();  // the ONLY barrier per step
    // gate phase: thread (gb, up) -> local units 2up, 2up+1
    float s[8];
#pragma unroll
    for (int k = 0; k < 8; ++k)
      s[k] = part[p][0][gb][up * 8 + k] + part[p][1][gb][up * 8 + k] +
             part[p][2][gb][up * 8 + k] + part[p][3][gb][up * 8 + k];
    float hA, hB;
    {
      const float si = s[0] + gxv0.x, sj = s[1] + gxv0.y;
      const float sf_ = s[2] + gxv0.z, so = s[3] + gxv0.w;
      const float ig = 1.f / (1.f + __expf(-si));
      const float jg = 1.f - 2.f / (__expf(2.f * sj) + 1.f);
      const float fg = 1.f / (1.f + __expf(-sf_));
      const float og = 1.f / (1.f + __expf(-so));
      cs0 = fg * cs0 + ig * jg;
      hA = og * (1.f - 2.f / (__expf(2.f * cs0) + 1.f));
    }
    {
      const float si = s[4] + gxv1.x, sj = s[5] + gxv1.y;
      const float sf_ = s[6] + gxv1.z, so = s[7] + gxv1.w;
      const float ig = 1.f / (1.f + __expf(-si));
      const float jg = 1.f - 2.f / (__expf(2.f * sj) + 1.f);
      const float fg = 1.f / (1.f + __expf(-sf_));
      const float og = 1.f / (1.f + __expf(-so));
      cs1 = fg * cs1 + ig * jg;
      hB = og * (1.f - 2.f / (__expf(2.f * cs1) + 1.f));
    }
    const u32 myw = (u32)f2bf(hA) | ((u32)f2bf(hB) << 16);
    const u32 otherw = (u32)__shfl_down((int)myw, 1);  // lane+1 = (gb, up+1)
    if (!(up & 1)) {  // even up: publish u64 covering local units 2up..2up+3
      u64 w64 = (u64)myw | ((u64)otherw << 32);
      u64* dst = (u64*)(hbuf + (size_t)(t + 1) * 16384 + gb * 1024 + g * 32 + up * 2);
      __hip_atomic_store(dst, w64, __ATOMIC_RELAXED, __HIP_MEMORY_SCOPE_AGENT);
    }
    // no second barrier: next step writes parity p^1 (read two steps ago)
  }
}

// ---------------- host ----------------

extern "C" void kernel_launch(void* const* d_in, const int* in_sizes, int n_in,
                              void* d_out, int out_size, void* d_ws, size_t ws_size,
                              hipStream_t stream) {
  const float* x        = (const float*)d_in[0];
  const float* mem      = (const float*)d_in[1];
  const float* src_bias = (const float*)d_in[2];
  const float* w_src_q = (const float*)d_in[4];  const float* b_src_q = (const float*)d_in[5];
  const float* w_src_k = (const float*)d_in[6];  const float* b_src_k = (const float*)d_in[7];
  const float* w_src_v = (const float*)d_in[8];  const float* b_src_v = (const float*)d_in[9];
  const float* w_src_o = (const float*)d_in[10]; const float* b_src_o = (const float*)d_in[11];
  const float* w_tgt_q = (const float*)d_in[12]; const float* b_tgt_q = (const float*)d_in[13];
  const float* w_tgt_k = (const float*)d_in[14]; const float* b_tgt_k = (const float*)d_in[15];
  const float* w_tgt_v = (const float*)d_in[16]; const float* b_tgt_v = (const float*)d_in[17];
  const float* w_tgt_o = (const float*)d_in[18]; const float* b_tgt_o = (const float*)d_in[19];
  const float* lstm_w  = (const float*)d_in[20]; const float* lstm_b  = (const float*)d_in[21];
  const float* w1 = (const float*)d_in[22]; const float* b1f = (const float*)d_in[23];
  const float* w2 = (const float*)d_in[24]; const float* b2f = (const float*)d_in[25];

  char* ws = (char*)d_ws;
  const size_t MiB = 1024ull * 1024ull;
  u16*   xcb  = (u16*)(ws + 0);             // [8192][2048]: cols 0-1023 x, 1024+ c
  u16*   wlp  = (u16*)(ws + 32 * MiB);      // [4096 packed][2048]
  u16*   whp  = (u16*)(ws + 48 * MiB);      // [4096 packed][1024]
  u16*   w1t  = (u16*)(ws + 56 * MiB);
  u16*   w2t  = (u16*)(ws + 64 * MiB);
  float* pb   = (float*)(ws + 72 * MiB);    // packed lstm bias [4096]
  u16*   hbuf = (u16*)(ws + 73 * MiB);      // [513][16][1024]
  u16*   memb = (u16*)(ws + 90 * MiB);
  u16*   wt[8];
  for (int i = 0; i < 8; ++i) wt[i] = (u16*)(ws + 106 * MiB + (size_t)i * 2 * MiB);
  u16*   bq   = (u16*)(ws + 122 * MiB);
  u16*   bk   = (u16*)(ws + 138 * MiB);
  u16*   bv   = (u16*)(ws + 154 * MiB);
  u16*   ao_s = (u16*)(ws + 170 * MiB);
  u16*   ao_t = (u16*)(ws + 186 * MiB);
  float* c32  = (float*)(ws + 202 * MiB);   // ..234
  float* gx   = (float*)(ws + 90 * MiB);    // overlay 90..218 (after attention)
  u16*   ffn1 = (u16*)(ws + 90 * MiB);      // overlay 90..154 (after scan)

  // sentinel-fill h rows 1..512 FIRST (L2 copies evicted by ~1ms of GEMM
  // traffic before FFN's cached reads; scan polls via L2-bypass regardless)
  hipMemsetAsync(hbuf + 16384, 0xFF, (size_t)512 * 16384 * 2, stream);
  hipMemsetAsync(hbuf, 0, 32768, stream);   // h_0 = 0

  // --- conversions ---
  cvt_x_kernel<<<8192, 256, 0, stream>>>(xcb, x);
  cvt_bf16_kernel<<<8192, 256, 0, stream>>>(memb, mem, 2097152);
  const dim3 g1k(32, 32);
  convt_kernel<<<g1k, 256, 0, stream>>>(wt[0], w_src_q, 1024, 1024, 0, 0.125f);
  convt_kernel<<<g1k, 256, 0, stream>>>(wt[1], w_src_k, 1024, 1024, 0, 1.f);
  convt_kernel<<<g1k, 256, 0, stream>>>(wt[2], w_src_v, 1024, 1024, 0, 1.f);
  convt_kernel<<<g1k, 256, 0, stream>>>(wt[3], w_src_o, 1024, 1024, 0, 1.f);
  convt_kernel<<<g1k, 256, 0, stream>>>(wt[4], w_tgt_q, 1024, 1024, 0, 0.125f);
  convt_kernel<<<g1k, 256, 0, stream>>>(wt[5], w_tgt_k, 1024, 1024, 0, 1.f);
  convt_kernel<<<g1k, 256, 0, stream>>>(wt[6], w_tgt_v, 1024, 1024, 0, 1.f);
  convt_kernel<<<g1k, 256, 0, stream>>>(wt[7], w_tgt_o, 1024, 1024, 0, 1.f);
  convt_perm_kernel<<<dim3(32, 64, 4), 256, 0, stream>>>(wlp, lstm_w, 2048, 0);
  convt_perm_kernel<<<dim3(32, 32, 4), 256, 0, stream>>>(whp, lstm_w, 1024, 2048);
  convt_kernel<<<dim3(128, 32), 256, 0, stream>>>(w1t, w1, 1024, 4096, 0, 1.f);
  convt_kernel<<<dim3(32, 128), 256, 0, stream>>>(w2t, w2, 4096, 1024, 0, 1.f);
  pack_bias_kernel<<<16, 256, 0, stream>>>(pb, lstm_b);

  const dim3 gN1(8, 64);   // N=1024
  const dim3 gN4(32, 64);  // N=4096

  // --- src attention ---
  gemm_bt_kernel<1, 0, 0, 0><<<gN1, 256, 0, stream>>>(xcb, 2048, wt[0], b_src_q, 0.125f, bq, 1024, nullptr, 0, 1024);
  gemm_bt_kernel<1, 0, 0, 0><<<gN1, 256, 0, stream>>>(memb, 1024, wt[1], b_src_k, 1.f, bk, 1024, nullptr, 0, 1024);
  gemm_bt_kernel<1, 0, 0, 0><<<gN1, 256, 0, stream>>>(memb, 1024, wt[2], b_src_v, 1.f, bv, 1024, nullptr, 0, 1024);
  flash_kernel<0><<<dim3(8, 16, 16), 256, 0, stream>>>(bq, bk, bv, src_bias, ao_s);
  // --- tgt (causal self) attention ---
  gemm_bt_kernel<1, 0, 0, 0><<<gN1, 256, 0, stream>>>(xcb, 2048, wt[4], b_tgt_q, 0.125f, bq, 1024, nullptr, 0, 1024);
  gemm_bt_kernel<1, 0, 0, 0><<<gN1, 256, 0, stream>>>(xcb, 2048, wt[5], b_tgt_k, 1.f, bk, 1024, nullptr, 0, 1024);
  gemm_bt_kernel<1, 0, 0, 0><<<gN1, 256, 0, stream>>>(xcb, 2048, wt[6], b_tgt_v, 1.f, bv, 1024, nullptr, 0, 1024);
  flash_kernel<1><<<dim3(8, 16, 16), 256, 0, stream>>>(bq, bk, bv, nullptr, ao_t);
  // --- c = ao_s@Wo_s + bo_s + ao_t@Wo_t + bo_t -> xcb cols 1024+ (bf16) ---
  gemm_bt_kernel<0, 0, 0, 0><<<gN1, 256, 0, stream>>>(ao_s, 1024, wt[3], b_src_o, 1.f, c32, 1024, nullptr, 0, 1024);
  gemm_bt_kernel<1, 1, 0, 0><<<gN1, 256, 0, stream>>>(ao_t, 1024, wt[7], b_tgt_o, 1.f, xcb + 1024, 2048, c32, 1024, 1024);
  // --- gx = [x|c] @ wlp^T + pb  (K=2048, packed cols) ---
  gemm_bt_kernel<0, 0, 0, 0><<<gN4, 256, 0, stream>>>(xcb, 2048, wlp, pb, 1.f, gx, 4096, nullptr, 0, 2048);
  // --- LSTM scan: single persistent kernel, 32 WGs (all co-resident) ---
  lstm_scan_kernel<<<dim3(SCAN_NW), 256, 0, stream>>>(whp, gx, hbuf);
  // --- FFN ---
  gemm_bt_kernel<1, 0, 1, 0><<<gN4, 256, 0, stream>>>(hbuf + 16384, 1024, w1t, b1f, 1.f, ffn1, 4096, nullptr, 0, 1024);
  gemm_bt_kernel<0, 0, 0, 2><<<gN1, 256, 0, stream>>>(ffn1, 4096, w2t, b2f, 1.f, (float*)d_out, 1024, nullptr, 0, 4096);
}